// Round 1
// baseline (644.896 us; speedup 1.0000x reference)
//
#include <hip/hip_runtime.h>
#include <math.h>

#define B_  32
#define S_  2048
#define DV  1024
#define U_  1024

typedef __attribute__((ext_vector_type(8))) short bf16x8;
typedef __attribute__((ext_vector_type(4))) float f32x4;

__device__ inline unsigned short f2bf(float f) {
    unsigned int x = __float_as_uint(f);
    return (unsigned short)((x + 0x7fffu + ((x >> 16) & 1u)) >> 16);
}

__device__ inline float tanh_fast(float x) {
    float ax = fabsf(x);
    float e  = __expf(ax + ax);
    float t  = 1.0f - __fdividef(2.0f, e + 1.0f);
    return copysignf(t, x);
}

// async global->LDS, 16B per lane; LDS dest must be the wave-uniform base
// (HW adds lane*16 itself). Global ptr is per-lane.
__device__ __forceinline__ void gload16(const void* g, void* l) {
    __builtin_amdgcn_global_load_lds(
        (const __attribute__((address_space(1))) void*)g,
        (__attribute__((address_space(3))) void*)l,
        16, 0, 0);
}

// ---------------- K0: t[b,u] = b1[u]+b2[u]; zero ctx + scores ---------------
__global__ void init_kernel(const float* __restrict__ b1, const float* __restrict__ b2,
                            float* __restrict__ t, float* __restrict__ ctx,
                            float* __restrict__ scores) {
    int i = blockIdx.x * 256 + threadIdx.x;   // 65536
    scores[i] = 0.f;
    if (i < B_ * U_) {
        int u = i & (U_ - 1);
        t[i]   = b1[u] + b2[u];
        ctx[i] = 0.f;
    }
}

// ---------------- K1: t[b,u] += query[b,:] @ W2[:,u] ------------------------
__global__ void projq_kernel(const float* __restrict__ q, const float* __restrict__ W2,
                             float* __restrict__ t) {
    int b  = blockIdx.x;
    int ks = blockIdx.y;
    int tid = threadIdx.x;
    __shared__ float qs[256];
    qs[tid] = q[b * DV + ks * 256 + tid];
    __syncthreads();
    float a0 = 0.f, a1 = 0.f, a2 = 0.f, a3 = 0.f;
    const float* w = W2 + (size_t)(ks * 256) * U_;
    for (int d = 0; d < 256; ++d) {
        float qd = qs[d];
        const float* wr = w + (size_t)d * U_ + tid;
        a0 += qd * wr[0];
        a1 += qd * wr[256];
        a2 += qd * wr[512];
        a3 += qd * wr[768];
    }
    atomicAdd(&t[b * U_ + tid      ], a0);
    atomicAdd(&t[b * U_ + tid + 256], a1);
    atomicAdd(&t[b * U_ + tid + 512], a2);
    atomicAdd(&t[b * U_ + tid + 768], a3);
}

// ---------------- prep: values fp32 -> bf16 ---------------------------------
__global__ void cvt_values(const float* __restrict__ v, unsigned short* __restrict__ o) {
    size_t i = ((size_t)blockIdx.x * 256 + threadIdx.x) * 8;
    float4 f0 = *(const float4*)(v + i);
    float4 f1 = *(const float4*)(v + i + 4);
    union { unsigned short s[8]; uint4 u; } p;
    p.s[0] = f2bf(f0.x); p.s[1] = f2bf(f0.y); p.s[2] = f2bf(f0.z); p.s[3] = f2bf(f0.w);
    p.s[4] = f2bf(f1.x); p.s[5] = f2bf(f1.y); p.s[6] = f2bf(f1.z); p.s[7] = f2bf(f1.w);
    *(uint4*)(o + i) = p.u;
}

// ---------------- prep: W1 [k][u] fp32 -> W1T [u][k] bf16 -------------------
__global__ void prep_w1t(const float* __restrict__ W1, unsigned short* __restrict__ W1T) {
    __shared__ float tile[64][65];
    int k0 = blockIdx.x * 64, u0 = blockIdx.y * 64;
    int t = threadIdx.x;
    int lr = t >> 4, lc = (t & 15) * 4;
#pragma unroll
    for (int i = 0; i < 4; ++i) {
        float4 f = *(const float4*)&W1[(size_t)(k0 + lr + i * 16) * U_ + u0 + lc];
        tile[lr + i * 16][lc + 0] = f.x; tile[lr + i * 16][lc + 1] = f.y;
        tile[lr + i * 16][lc + 2] = f.z; tile[lr + i * 16][lc + 3] = f.w;
    }
    __syncthreads();
    int ur = t >> 2, kq = (t & 3) * 16;
    union { unsigned short s[8]; uint4 u; } p0, p1;
#pragma unroll
    for (int e = 0; e < 8; ++e) p0.s[e] = f2bf(tile[kq + e][ur]);
#pragma unroll
    for (int e = 0; e < 8; ++e) p1.s[e] = f2bf(tile[kq + 8 + e][ur]);
    unsigned short* dst = W1T + (size_t)(u0 + ur) * 1024 + k0 + kq;
    *(uint4*)dst       = p0.u;
    *(uint4*)(dst + 8) = p1.u;
}

// ---------------- K2 v2: 256x128 tile, BK=32, global_load_lds, dbuf ---------
// 4 waves (2 row-halves x 2 col-halves), wave tile 128x64 (acc 8x4 f32x4).
// LDS: row-paired 128B lines, chunk ^= (line&7) swizzle (<=2-way, balanced
// 8 accesses/bank). global_load_lds writes linearly -> inverse-swizzled
// GLOBAL source per lane (both-sides-or-neither).
// One __syncthreads per K-tile; next tile's 6 loads issued at tile top so the
// barrier's vmcnt(0) waits on ~1200-cycle-old loads (covered by L2/HBM lat).
// 48KB LDS + ~210 VGPR -> 2 independent blocks/CU for cross-block overlap.
__launch_bounds__(256, 2)
__global__ void scores_mfma2(const unsigned short* __restrict__ Abf,
                             const unsigned short* __restrict__ W1T,
                             const float* __restrict__ tvec,
                             const float* __restrict__ V,
                             float* __restrict__ scores) {
    __shared__ unsigned short sA[2 * 128 * 64];  // 2 bufs x 16KB (A: 256 rows x 32k)
    __shared__ unsigned short sB[2 * 64 * 64];   // 2 bufs x  8KB (B: 128 rows x 32k)

    const int tid  = threadIdx.x;
    const int lane = tid & 63;
    const int wave = tid >> 6;        // 0..3
    const int wm   = wave & 1;        // row half: 128 rows
    const int wn   = wave >> 1;       // col half: 64 cols
    const int l15  = lane & 15;
    const int lq   = lane >> 4;       // 0..3

    // XCD swizzle: ids 0..7 hit XCDs 0..7 with distinct A-panels (utile 0);
    // the next 7 utile passes re-read the same A-panel from that XCD's L2.
    const int id    = blockIdx.x;                    // 0..2047
    const int utile = (id >> 3) & 7;                 // 8 u-tiles of 128
    const int stile = (id & 7) | ((id >> 6) << 3);   // 256 s-tiles of 256
    const size_t row0 = (size_t)stile * 256;
    const int b       = (int)(row0 >> 11);
    const int s_local = (int)(row0 & 2047);
    const int u0      = utile * 128;

    // ---- staging descriptors: linear LDS dest, inverse-swizzled global src
    const unsigned short* aS[4];
    const unsigned short* bS[2];
    char* aD[4];
    char* bD[2];
#pragma unroll
    for (int j = 0; j < 4; ++j) {
        int L = j * 4096 + tid * 16;          // linear byte in 16KB A tile
        int line = L >> 7, p = (L >> 4) & 7;  // 128B line, 16B chunk
        int c = p ^ (line & 7);               // logical chunk
        int row = line * 2 + (c >> 2);        // row-paired: 2 rows per line
        int kq = c & 3;                       // 8-elem k chunk
        aS[j] = Abf + (row0 + row) * 1024 + kq * 8;
        aD[j] = (char*)sA + j * 4096 + wave * 1024;   // wave-uniform base
    }
#pragma unroll
    for (int j = 0; j < 2; ++j) {
        int L = j * 4096 + tid * 16;          // linear byte in 8KB B tile
        int line = L >> 7, p = (L >> 4) & 7;
        int c = p ^ (line & 7);
        int row = line * 2 + (c >> 2);
        int kq = c & 3;
        bS[j] = W1T + (size_t)(u0 + row) * 1024 + kq * 8;
        bD[j] = (char*)sB + j * 4096 + wave * 1024;
    }

    // frag-read bases: line&7 == (l15>>1)&7 independent of m/n -> constant
    // per-lane swizzled chunk, frags at stride 512 ushorts.
    const int prd = ((l15 & 1) * 4 + lq) ^ ((l15 >> 1) & 7);
    const unsigned short* paBase = sA + (wm * 64 + (l15 >> 1)) * 64 + prd * 8;
    const unsigned short* pbBase = sB + (wn * 32 + (l15 >> 1)) * 64 + prd * 8;

    f32x4 acc[8][4];
#pragma unroll
    for (int m = 0; m < 8; ++m)
#pragma unroll
        for (int n = 0; n < 4; ++n) acc[m][n] = (f32x4)0.f;

    // prologue: stage K-tile 0 into buf 0
#pragma unroll
    for (int j = 0; j < 4; ++j) gload16(aS[j], aD[j]);
#pragma unroll
    for (int j = 0; j < 2; ++j) gload16(bS[j], bD[j]);
#pragma unroll
    for (int j = 0; j < 4; ++j) aS[j] += 32;
#pragma unroll
    for (int j = 0; j < 2; ++j) bS[j] += 32;
    __syncthreads();

    for (int kt = 0; kt < 32; ++kt) {
        const int cur = kt & 1;
        if (kt < 31) {                 // issue next tile's stage EARLY
            const int nb = cur ^ 1;
#pragma unroll
            for (int j = 0; j < 4; ++j) gload16(aS[j], aD[j] + nb * 16384);
#pragma unroll
            for (int j = 0; j < 2; ++j) gload16(bS[j], bD[j] + nb * 8192);
#pragma unroll
            for (int j = 0; j < 4; ++j) aS[j] += 32;
#pragma unroll
            for (int j = 0; j < 2; ++j) bS[j] += 32;
        }
        const unsigned short* pa = paBase + cur * 8192;
        const unsigned short* pb = pbBase + cur * 4096;
        bf16x8 af[8], bfr[4];
#pragma unroll
        for (int m = 0; m < 8; ++m) af[m] = *(const bf16x8*)(pa + m * 512);
#pragma unroll
        for (int n = 0; n < 4; ++n) bfr[n] = *(const bf16x8*)(pb + n * 512);
        __builtin_amdgcn_s_setprio(1);
#pragma unroll
        for (int n = 0; n < 4; ++n)
#pragma unroll
            for (int m = 0; m < 8; ++m)
                acc[m][n] = __builtin_amdgcn_mfma_f32_16x16x32_bf16(af[m], bfr[n], acc[m][n], 0, 0, 0);
        __builtin_amdgcn_s_setprio(0);
        __syncthreads();               // drains vmcnt(0): waits on loads issued
                                       // one full tile earlier -> ~free
    }

    // epilogue: score[row] += sum_u tanh(P + t[b,u]) * V[u]
    float* fscore = (float*)sA;        // reuse LDS (all reads drained above)
    fscore[tid] = 0.f;
    __syncthreads();
    float tu[4], vu[4];
#pragma unroll
    for (int n = 0; n < 4; ++n) {
        int u = u0 + wn * 64 + n * 16 + l15;
        tu[n] = tvec[b * U_ + u];
        vu[n] = V[u];
    }
#pragma unroll
    for (int m = 0; m < 8; ++m) {
#pragma unroll
        for (int r = 0; r < 4; ++r) {
            float p = 0.f;
#pragma unroll
            for (int n = 0; n < 4; ++n) p += tanh_fast(acc[m][n][r] + tu[n]) * vu[n];
            p += __shfl_xor(p, 1);
            p += __shfl_xor(p, 2);
            p += __shfl_xor(p, 4);
            p += __shfl_xor(p, 8);
            if (l15 == 0) atomicAdd(&fscore[wm * 128 + m * 16 + lq * 4 + r], p);
        }
    }
    __syncthreads();
    atomicAdd(&scores[(size_t)b * S_ + s_local + tid], fscore[tid]);
}

// ---------------- K2 (legacy): MFMA scores GEMM, reg-staged -----------------
// kept for the mid path (fp32 A converted in-kernel).
template<bool ABF16>
__launch_bounds__(256, 2)
__global__ void scores_mfma(const void* __restrict__ aPtr,
                            const unsigned short* __restrict__ W1T,
                            const float* __restrict__ t,
                            const float* __restrict__ V,
                            float* __restrict__ scores) {
    __shared__ unsigned short sA[128 * 40];
    __shared__ unsigned short sB[256 * 40];
    __shared__ float fscore[128];

    const int tid  = threadIdx.x;
    const int lane = tid & 63;
    const int wave = tid >> 6;
    const int wm = wave & 1, wn = wave >> 1;
    const int l15 = lane & 15, lq = lane >> 4;

    const int id    = blockIdx.x;
    const int utile = (id >> 3) & 3;
    const int stile = (id & 7) | ((id >> 5) << 3);
    const size_t row0 = (size_t)stile * 128;
    const int b       = (int)(row0 >> 11);
    const int s_local = (int)(row0 & 2047);
    const int u0      = utile * 256;

    if (tid < 128) fscore[tid] = 0.f;

    const int ar = tid >> 1, ak = (tid & 1) << 4;
    const int br = tid >> 1, bk = (tid & 1) << 4;

    const float* Af = (const float*)aPtr + (row0 + ar) * 1024 + ak;
    const unsigned short* Ab = (const unsigned short*)aPtr + (row0 + ar) * 1024 + ak;
    const unsigned short* Bp0 = W1T + (size_t)(u0 + br) * 1024 + bk;
    const unsigned short* Bp1 = Bp0 + 128 * 1024;

    f32x4 acc[4][8];
#pragma unroll
    for (int i = 0; i < 4; ++i)
#pragma unroll
        for (int j = 0; j < 8; ++j) acc[i][j] = (f32x4)0.f;

    uint4 sa0, sa1, sb0, sb1, sb2, sb3;
    float4 fa0, fa1, fa2, fa3;

    if (ABF16) {
        sa0 = *(const uint4*)(Ab);
        sa1 = *(const uint4*)(Ab + 8);
    } else {
        fa0 = *(const float4*)(Af);
        fa1 = *(const float4*)(Af + 4);
        fa2 = *(const float4*)(Af + 8);
        fa3 = *(const float4*)(Af + 12);
    }
    sb0 = *(const uint4*)(Bp0);
    sb1 = *(const uint4*)(Bp0 + 8);
    sb2 = *(const uint4*)(Bp1);
    sb3 = *(const uint4*)(Bp1 + 8);

    for (int k0 = 0; k0 < 1024; k0 += 32) {
        __syncthreads();
        if (ABF16) {
            *(uint4*)&sA[ar * 40 + ak]     = sa0;
            *(uint4*)&sA[ar * 40 + ak + 8] = sa1;
        } else {
            union { unsigned short s[8]; uint4 u; } p0, p1;
            p0.s[0] = f2bf(fa0.x); p0.s[1] = f2bf(fa0.y); p0.s[2] = f2bf(fa0.z); p0.s[3] = f2bf(fa0.w);
            p0.s[4] = f2bf(fa1.x); p0.s[5] = f2bf(fa1.y); p0.s[6] = f2bf(fa1.z); p0.s[7] = f2bf(fa1.w);
            p1.s[0] = f2bf(fa2.x); p1.s[1] = f2bf(fa2.y); p1.s[2] = f2bf(fa2.z); p1.s[3] = f2bf(fa2.w);
            p1.s[4] = f2bf(fa3.x); p1.s[5] = f2bf(fa3.y); p1.s[6] = f2bf(fa3.z); p1.s[7] = f2bf(fa3.w);
            *(uint4*)&sA[ar * 40 + ak]     = p0.u;
            *(uint4*)&sA[ar * 40 + ak + 8] = p1.u;
        }
        *(uint4*)&sB[br * 40 + bk]           = sb0;
        *(uint4*)&sB[br * 40 + bk + 8]       = sb1;
        *(uint4*)&sB[(br + 128) * 40 + bk]     = sb2;
        *(uint4*)&sB[(br + 128) * 40 + bk + 8] = sb3;

        if (k0 + 32 < 1024) {
            int nk = k0 + 32;
            if (ABF16) {
                sa0 = *(const uint4*)(Ab + nk);
                sa1 = *(const uint4*)(Ab + nk + 8);
            } else {
                fa0 = *(const float4*)(Af + nk);
                fa1 = *(const float4*)(Af + nk + 4);
                fa2 = *(const float4*)(Af + nk + 8);
                fa3 = *(const float4*)(Af + nk + 12);
            }
            sb0 = *(const uint4*)(Bp0 + nk);
            sb1 = *(const uint4*)(Bp0 + nk + 8);
            sb2 = *(const uint4*)(Bp1 + nk);
            sb3 = *(const uint4*)(Bp1 + nk + 8);
        }
        __syncthreads();

        bf16x8 af[4];
#pragma unroll
        for (int i = 0; i < 4; ++i)
            af[i] = *(const bf16x8*)&sA[(64 * wm + 16 * i + l15) * 40 + lq * 8];
#pragma unroll
        for (int j = 0; j < 8; ++j) {
            bf16x8 bfj = *(const bf16x8*)&sB[(128 * wn + 16 * j + l15) * 40 + lq * 8];
#pragma unroll
            for (int i = 0; i < 4; ++i)
                acc[i][j] = __builtin_amdgcn_mfma_f32_16x16x32_bf16(af[i], bfj, acc[i][j], 0, 0, 0);
        }
    }

    float tu[8], vu[8];
#pragma unroll
    for (int j = 0; j < 8; ++j) {
        int u = u0 + 128 * wn + 16 * j + l15;
        tu[j] = t[b * U_ + u];
        vu[j] = V[u];
    }
#pragma unroll
    for (int i = 0; i < 4; ++i) {
#pragma unroll
        for (int r = 0; r < 4; ++r) {
            float p = 0.f;
#pragma unroll
            for (int j = 0; j < 8; ++j) p += tanh_fast(acc[i][j][r] + tu[j]) * vu[j];
            p += __shfl_xor(p, 1);
            p += __shfl_xor(p, 2);
            p += __shfl_xor(p, 4);
            p += __shfl_xor(p, 8);
            if (l15 == 0) atomicAdd(&fscore[64 * wm + 16 * i + lq * 4 + r], p);
        }
    }
    __syncthreads();
    if (tid < 128) atomicAdd(&scores[(size_t)b * S_ + s_local + tid], fscore[tid]);
}

// ---------------- K2-low: fp32 vector scores (last-resort ws fallback) ------
__launch_bounds__(256, 2)
__global__ void scores_vec(const float* __restrict__ values, const float* __restrict__ W1,
                           const float* __restrict__ t, const float* __restrict__ V,
                           float* __restrict__ scores) {
    __shared__ float vA[16][132];
    __shared__ float vB[16][68];
    __shared__ float fscore[128];
    const int b   = blockIdx.y;
    const int s0  = blockIdx.x * 128;
    const int tid = threadIdx.x;
    const int tx  = tid & 15, ty = tid >> 4;
    if (tid < 128) fscore[tid] = 0.f;
    const float* vbase = values + ((size_t)b * S_ + s0) * (size_t)DV;
    const int lm = tid >> 2, lkq = (tid & 3) * 4;
    const int lbk = tid >> 4, lbj = (tid & 15) * 4;
    for (int nt = 0; nt < U_ / 64; ++nt) {
        const int u0 = nt * 64;
        float acc[8][4];
#pragma unroll
        for (int i = 0; i < 8; ++i)
#pragma unroll
            for (int j = 0; j < 4; ++j) acc[i][j] = 0.f;
        for (int k0 = 0; k0 < DV; k0 += 16) {
            __syncthreads();
            const float4 v0 = *(const float4*)(vbase + (size_t)lm * DV + k0 + lkq);
            const float4 v1 = *(const float4*)(vbase + (size_t)(lm + 64) * DV + k0 + lkq);
            vA[lkq + 0][lm] = v0.x; vA[lkq + 1][lm] = v0.y;
            vA[lkq + 2][lm] = v0.z; vA[lkq + 3][lm] = v0.w;
            vA[lkq + 0][lm + 64] = v1.x; vA[lkq + 1][lm + 64] = v1.y;
            vA[lkq + 2][lm + 64] = v1.z; vA[lkq + 3][lm + 64] = v1.w;
            *(float4*)&vB[lbk][lbj] = *(const float4*)(W1 + (size_t)(k0 + lbk) * U_ + u0 + lbj);
            __syncthreads();
#pragma unroll
            for (int k = 0; k < 16; ++k) {
                float4 va0 = *(const float4*)&vA[k][ty * 8];
                float4 va1 = *(const float4*)&vA[k][ty * 8 + 4];
                float4 vb  = *(const float4*)&vB[k][tx * 4];
                float a_[8] = {va0.x, va0.y, va0.z, va0.w, va1.x, va1.y, va1.z, va1.w};
                float b_[4] = {vb.x, vb.y, vb.z, vb.w};
#pragma unroll
                for (int i = 0; i < 8; ++i)
#pragma unroll
                    for (int j = 0; j < 4; ++j) acc[i][j] += a_[i] * b_[j];
            }
        }
        float tq[4], vv[4];
#pragma unroll
        for (int j = 0; j < 4; ++j) {
            int u = u0 + tx * 4 + j;
            tq[j] = t[b * U_ + u];
            vv[j] = V[u];
        }
#pragma unroll
        for (int i = 0; i < 8; ++i) {
            float p = 0.f;
#pragma unroll
            for (int j = 0; j < 4; ++j) p += tanhf(acc[i][j] + tq[j]) * vv[j];
            p += __shfl_down(p, 8, 16);
            p += __shfl_down(p, 4, 16);
            p += __shfl_down(p, 2, 16);
            p += __shfl_down(p, 1, 16);
            if (tx == 0) fscore[ty * 8 + i] += p;
        }
    }
    __syncthreads();
    if (tid < 128) scores[(size_t)b * S_ + s0 + tid] = fscore[tid];
}

// ---------------- K3: softmax over S per batch ------------------------------
__global__ void softmax_kernel(const float* __restrict__ scores, float* __restrict__ wout) {
    int b = blockIdx.x;
    int tid = threadIdx.x;
    __shared__ float red[256];
    float v[8];
    float m = -1e30f;
#pragma unroll
    for (int i = 0; i < 8; ++i) {
        v[i] = scores[(size_t)b * S_ + tid + i * 256];
        m = fmaxf(m, v[i]);
    }
    red[tid] = m; __syncthreads();
    for (int off = 128; off > 0; off >>= 1) {
        if (tid < off) red[tid] = fmaxf(red[tid], red[tid + off]);
        __syncthreads();
    }
    m = red[0];
    __syncthreads();
    float s = 0.f;
#pragma unroll
    for (int i = 0; i < 8; ++i) { v[i] = __expf(v[i] - m); s += v[i]; }
    red[tid] = s; __syncthreads();
    for (int off = 128; off > 0; off >>= 1) {
        if (tid < off) red[tid] += red[tid + off];
        __syncthreads();
    }
    float inv = 1.f / red[0];
#pragma unroll
    for (int i = 0; i < 8; ++i) wout[(size_t)b * S_ + tid + i * 256] = v[i] * inv;
}

// ---------------- K4: context[b,d] = sum_s w[b,s] * values[b,s,d] -----------
__global__ void context_kernel(const float* __restrict__ values, const float* __restrict__ w,
                               float* __restrict__ ctx) {
    int b  = blockIdx.x;
    int dc = blockIdx.y;
    int sc = blockIdx.z;
    int tid = threadIdx.x;
    int d = dc * 256 + tid;
    __shared__ float ws_[256];
    ws_[tid] = w[(size_t)b * S_ + sc * 256 + tid];
    __syncthreads();
    float acc = 0.f;
    const float* vp = values + ((size_t)b * S_ + sc * 256) * (size_t)DV + d;
#pragma unroll 4
    for (int s = 0; s < 256; ++s) acc += ws_[s] * vp[(size_t)s * DV];
    atomicAdd(&ctx[b * DV + d], acc);
}

// ---------------- launch ----------------------------------------------------
extern "C" void kernel_launch(void* const* d_in, const int* in_sizes, int n_in,
                              void* d_out, int out_size, void* d_ws, size_t ws_size,
                              hipStream_t stream) {
    const float* query  = (const float*)d_in[0];
    const float* values = (const float*)d_in[1];
    const float* W1     = (const float*)d_in[2];
    const float* b1     = (const float*)d_in[3];
    const float* W2     = (const float*)d_in[4];
    const float* b2     = (const float*)d_in[5];
    const float* V      = (const float*)d_in[6];
    // bV (d_in[7]) shifts all scores equally -> softmax-invariant.

    float* out  = (float*)d_out;
    float* ctx  = out;                 // [32, 1024]
    float* wout = out + B_ * DV;       // [32, 2048]

    char* ws = (char*)d_ws;
    const size_t W1T_BYTES = (size_t)U_ * DV * 2;              // 2 MB
    const size_t T_BYTES   = (size_t)B_ * U_ * 4;              // 128 KB
    const size_t SC_BYTES  = (size_t)B_ * S_ * 4;              // 256 KB
    const size_t ABF_BYTES = (size_t)B_ * S_ * DV * 2;         // 128 MB

    if (ws_size >= W1T_BYTES + T_BYTES + SC_BYTES + ABF_BYTES) {
        // fast path: bf16 A + bf16 W1T, gload_lds double-buffered MFMA
        unsigned short* W1T = (unsigned short*)ws;
        float* t      = (float*)(ws + W1T_BYTES);
        float* scores = t + B_ * U_;
        unsigned short* Abf = (unsigned short*)(scores + B_ * S_);

        init_kernel   <<<dim3(256),      256, 0, stream>>>(b1, b2, t, ctx, scores);
        projq_kernel  <<<dim3(32, 4),    256, 0, stream>>>(query, W2, t);
        cvt_values    <<<dim3(32768),    256, 0, stream>>>(values, Abf);
        prep_w1t      <<<dim3(16, 16),   256, 0, stream>>>(W1, W1T);
        scores_mfma2  <<<dim3(2048),     256, 0, stream>>>(Abf, W1T, t, V, scores);
        softmax_kernel<<<dim3(32),       256, 0, stream>>>(scores, wout);
        context_kernel<<<dim3(32, 4, 8), 256, 0, stream>>>(values, wout, ctx);
    } else if (ws_size >= W1T_BYTES + T_BYTES + SC_BYTES) {
        // mid path: fp32 A converted in-kernel, bf16 W1T, MFMA
        unsigned short* W1T = (unsigned short*)ws;
        float* t      = (float*)(ws + W1T_BYTES);
        float* scores = t + B_ * U_;

        init_kernel   <<<dim3(256),      256, 0, stream>>>(b1, b2, t, ctx, scores);
        projq_kernel  <<<dim3(32, 4),    256, 0, stream>>>(query, W2, t);
        prep_w1t      <<<dim3(16, 16),   256, 0, stream>>>(W1, W1T);
        scores_mfma<false><<<dim3(2048), 256, 0, stream>>>(values, W1T, t, V, scores);
        softmax_kernel<<<dim3(32),       256, 0, stream>>>(scores, wout);
        context_kernel<<<dim3(32, 4, 8), 256, 0, stream>>>(values, wout, ctx);
    } else {
        // low path: round-1 fp32 vector kernel (384 KB ws, proven)
        float* t      = (float*)ws;
        float* scores = t + B_ * U_;

        init_kernel   <<<dim3(256),      256, 0, stream>>>(b1, b2, t, ctx, scores);
        projq_kernel  <<<dim3(32, 4),    256, 0, stream>>>(query, W2, t);
        scores_vec    <<<dim3(16, 32),   256, 0, stream>>>(values, W1, t, V, scores);
        softmax_kernel<<<dim3(32),       256, 0, stream>>>(scores, wout);
        context_kernel<<<dim3(32, 4, 8), 256, 0, stream>>>(values, wout, ctx);
    }
}

// Round 2
// 634.746 us; speedup vs baseline: 1.0160x; 1.0160x over previous
//
#include <hip/hip_runtime.h>
#include <math.h>

#define B_  32
#define S_  2048
#define DV  1024
#define U_  1024

typedef __attribute__((ext_vector_type(8))) short bf16x8;
typedef __attribute__((ext_vector_type(4))) float f32x4;

__device__ inline unsigned short f2bf(float f) {
    unsigned int x = __float_as_uint(f);
    return (unsigned short)((x + 0x7fffu + ((x >> 16) & 1u)) >> 16);
}

__device__ inline float tanh_fast(float x) {
    float ax = fabsf(x);
    float e  = __expf(ax + ax);
    float t  = 1.0f - __fdividef(2.0f, e + 1.0f);
    return copysignf(t, x);
}

// async global->LDS, 16B per lane; LDS dest is the wave-uniform base
// (HW adds lane*16 itself). Global ptr is per-lane.
__device__ __forceinline__ void gload16(const void* g, void* l) {
    __builtin_amdgcn_global_load_lds(
        (const __attribute__((address_space(1))) void*)g,
        (__attribute__((address_space(3))) void*)l,
        16, 0, 0);
}

// ---------------- K0: t[b,u] = b1[u]+b2[u]; zero ctx + scores ---------------
__global__ void init_kernel(const float* __restrict__ b1, const float* __restrict__ b2,
                            float* __restrict__ t, float* __restrict__ ctx,
                            float* __restrict__ scores) {
    int i = blockIdx.x * 256 + threadIdx.x;   // 65536
    scores[i] = 0.f;
    if (i < B_ * U_) {
        int u = i & (U_ - 1);
        t[i]   = b1[u] + b2[u];
        ctx[i] = 0.f;
    }
}

// ---------------- K1: t[b,u] += query[b,:] @ W2[:,u] ------------------------
// widened: 512 blocks (was 128 -> half the GPU idle)
__global__ void projq_kernel(const float* __restrict__ q, const float* __restrict__ W2,
                             float* __restrict__ t) {
    int b  = blockIdx.x;        // 32
    int ks = blockIdx.y;        // 16 chunks of 64 k-rows
    int tid = threadIdx.x;
    __shared__ float qs[64];
    if (tid < 64) qs[tid] = q[b * DV + ks * 64 + tid];
    __syncthreads();
    float a0 = 0.f, a1 = 0.f, a2 = 0.f, a3 = 0.f;
    const float* w = W2 + (size_t)(ks * 64) * U_;
    for (int d = 0; d < 64; ++d) {
        float qd = qs[d];
        const float* wr = w + (size_t)d * U_ + tid;
        a0 += qd * wr[0];
        a1 += qd * wr[256];
        a2 += qd * wr[512];
        a3 += qd * wr[768];
    }
    atomicAdd(&t[b * U_ + tid      ], a0);
    atomicAdd(&t[b * U_ + tid + 256], a1);
    atomicAdd(&t[b * U_ + tid + 512], a2);
    atomicAdd(&t[b * U_ + tid + 768], a3);
}

// ---------------- prep: values fp32 -> bf16 ---------------------------------
__global__ void cvt_values(const float* __restrict__ v, unsigned short* __restrict__ o) {
    size_t i = ((size_t)blockIdx.x * 256 + threadIdx.x) * 8;
    float4 f0 = *(const float4*)(v + i);
    float4 f1 = *(const float4*)(v + i + 4);
    union { unsigned short s[8]; uint4 u; } p;
    p.s[0] = f2bf(f0.x); p.s[1] = f2bf(f0.y); p.s[2] = f2bf(f0.z); p.s[3] = f2bf(f0.w);
    p.s[4] = f2bf(f1.x); p.s[5] = f2bf(f1.y); p.s[6] = f2bf(f1.z); p.s[7] = f2bf(f1.w);
    *(uint4*)(o + i) = p.u;
}

// ---------------- prep: W1 [k][u] fp32 -> W1T [u][k] bf16 -------------------
__global__ void prep_w1t(const float* __restrict__ W1, unsigned short* __restrict__ W1T) {
    __shared__ float tile[64][65];
    int k0 = blockIdx.x * 64, u0 = blockIdx.y * 64;
    int t = threadIdx.x;
    int lr = t >> 4, lc = (t & 15) * 4;
#pragma unroll
    for (int i = 0; i < 4; ++i) {
        float4 f = *(const float4*)&W1[(size_t)(k0 + lr + i * 16) * U_ + u0 + lc];
        tile[lr + i * 16][lc + 0] = f.x; tile[lr + i * 16][lc + 1] = f.y;
        tile[lr + i * 16][lc + 2] = f.z; tile[lr + i * 16][lc + 3] = f.w;
    }
    __syncthreads();
    int ur = t >> 2, kq = (t & 3) * 16;
    union { unsigned short s[8]; uint4 u; } p0, p1;
#pragma unroll
    for (int e = 0; e < 8; ++e) p0.s[e] = f2bf(tile[kq + e][ur]);
#pragma unroll
    for (int e = 0; e < 8; ++e) p1.s[e] = f2bf(tile[kq + 8 + e][ur]);
    unsigned short* dst = W1T + (size_t)(u0 + ur) * 1024 + k0 + kq;
    *(uint4*)dst       = p0.u;
    *(uint4*)(dst + 8) = p1.u;
}

// ---------------- K2 v3: 256x128 tile, BK=32, 3-buffer counted-vmcnt --------
// Identical compute body to r1 (swizzle, frags, epilogue). Schedule changed:
// 3 LDS buffers (72 KB); at iter kt stage tile kt+2, then s_waitcnt vmcnt(6)
// (retire tile kt+1's 6 loads, leave kt+2's 6 in flight) + raw s_barrier.
// vmcnt never drains to 0 in steady state -> the end-of-tile wait targets
// loads issued one full iteration (+compute) earlier.
// Ring hazard audit: stage of tile kt+2 overwrites buf (kt+2)%3 == (kt-1)%3,
// whose readers all passed the kt-1 end barrier before this stage issues.
__launch_bounds__(256, 2)
__global__ void scores_mfma3(const unsigned short* __restrict__ Abf,
                             const unsigned short* __restrict__ W1T,
                             const float* __restrict__ tvec,
                             const float* __restrict__ V,
                             float* __restrict__ scores) {
    __shared__ unsigned short sA[3 * 8192];   // 3 bufs x 16 KB (A: 256 rows x 32k)
    __shared__ unsigned short sB[3 * 4096];   // 3 bufs x  8 KB (B: 128 rows x 32k)

    const int tid  = threadIdx.x;
    const int lane = tid & 63;
    const int wave = tid >> 6;        // 0..3
    const int wm   = wave & 1;        // row half: 128 rows
    const int wn   = wave >> 1;       // col half: 64 cols
    const int l15  = lane & 15;
    const int lq   = lane >> 4;       // 0..3

    // XCD swizzle: the 8 utile-passes over one A-strip land on one XCD's L2.
    const int id    = blockIdx.x;                    // 0..2047
    const int utile = (id >> 3) & 7;                 // 8 u-tiles of 128
    const int stile = (id & 7) | ((id >> 6) << 3);   // 256 s-tiles of 256
    const size_t row0 = (size_t)stile * 256;
    const int b       = (int)(row0 >> 11);
    const int s_local = (int)(row0 & 2047);
    const int u0      = utile * 128;

    // ---- staging descriptors: linear LDS dest, inverse-swizzled global src
    const unsigned short* aS[4];
    const unsigned short* bS[2];
    char* aD[4];
    char* bD[2];
#pragma unroll
    for (int j = 0; j < 4; ++j) {
        int L = j * 4096 + tid * 16;          // linear byte in 16KB A tile
        int line = L >> 7, p = (L >> 4) & 7;  // 128B line, 16B chunk
        int c = p ^ (line & 7);               // logical chunk
        int row = line * 2 + (c >> 2);        // row-paired: 2 rows per line
        int kq = c & 3;                       // 8-elem k chunk
        aS[j] = Abf + (row0 + row) * 1024 + kq * 8;
        aD[j] = (char*)sA + j * 4096 + wave * 1024;   // wave-uniform base
    }
#pragma unroll
    for (int j = 0; j < 2; ++j) {
        int L = j * 4096 + tid * 16;          // linear byte in 8KB B tile
        int line = L >> 7, p = (L >> 4) & 7;
        int c = p ^ (line & 7);
        int row = line * 2 + (c >> 2);
        int kq = c & 3;
        bS[j] = W1T + (size_t)(u0 + row) * 1024 + kq * 8;
        bD[j] = (char*)sB + j * 4096 + wave * 1024;
    }

    // frag-read bases: constant per-lane swizzled chunk, frags at stride 512.
    const int prd = ((l15 & 1) * 4 + lq) ^ ((l15 >> 1) & 7);
    const unsigned short* paBase = sA + (wm * 64 + (l15 >> 1)) * 64 + prd * 8;
    const unsigned short* pbBase = sB + (wn * 32 + (l15 >> 1)) * 64 + prd * 8;

    f32x4 acc[8][4];
#pragma unroll
    for (int m = 0; m < 8; ++m)
#pragma unroll
        for (int n = 0; n < 4; ++n) acc[m][n] = (f32x4)0.f;

    // prologue: stage tile 0 -> buf0, tile 1 -> buf1
#pragma unroll
    for (int j = 0; j < 4; ++j) gload16(aS[j], aD[j]);
#pragma unroll
    for (int j = 0; j < 2; ++j) gload16(bS[j], bD[j]);
#pragma unroll
    for (int j = 0; j < 4; ++j) aS[j] += 32;
#pragma unroll
    for (int j = 0; j < 2; ++j) bS[j] += 32;
#pragma unroll
    for (int j = 0; j < 4; ++j) gload16(aS[j], aD[j] + 16384);
#pragma unroll
    for (int j = 0; j < 2; ++j) gload16(bS[j], bD[j] + 8192);
#pragma unroll
    for (int j = 0; j < 4; ++j) aS[j] += 32;
#pragma unroll
    for (int j = 0; j < 2; ++j) bS[j] += 32;
    __builtin_amdgcn_sched_barrier(0);
    asm volatile("s_waitcnt vmcnt(6)" ::: "memory");   // tile 0 landed
    __builtin_amdgcn_s_barrier();
    __builtin_amdgcn_sched_barrier(0);

    int cb = 0;   // current buffer index
    int sb = 2;   // staging buffer index (tile kt+2)

    for (int kt = 0; kt < 32; ++kt) {
        if (kt < 30) {                 // issue tile kt+2's 6 loads FIRST
#pragma unroll
            for (int j = 0; j < 4; ++j) gload16(aS[j], aD[j] + sb * 16384);
#pragma unroll
            for (int j = 0; j < 2; ++j) gload16(bS[j], bD[j] + sb * 8192);
#pragma unroll
            for (int j = 0; j < 4; ++j) aS[j] += 32;
#pragma unroll
            for (int j = 0; j < 2; ++j) bS[j] += 32;
        }
        const unsigned short* pa = paBase + cb * 8192;
        const unsigned short* pb = pbBase + cb * 4096;
        bf16x8 af[8], bfr[4];
#pragma unroll
        for (int m = 0; m < 8; ++m) af[m] = *(const bf16x8*)(pa + m * 512);
#pragma unroll
        for (int n = 0; n < 4; ++n) bfr[n] = *(const bf16x8*)(pb + n * 512);
        __builtin_amdgcn_s_setprio(1);
#pragma unroll
        for (int n = 0; n < 4; ++n)
#pragma unroll
            for (int m = 0; m < 8; ++m)
                acc[m][n] = __builtin_amdgcn_mfma_f32_16x16x32_bf16(af[m], bfr[n], acc[m][n], 0, 0, 0);
        __builtin_amdgcn_s_setprio(0);

        __builtin_amdgcn_sched_barrier(0);
        if (kt < 30) {
            asm volatile("s_waitcnt vmcnt(6)" ::: "memory");  // tile kt+1 landed
        } else if (kt == 30) {
            asm volatile("s_waitcnt vmcnt(0)" ::: "memory");  // tile 31 landed (ring tail)
        }
        __builtin_amdgcn_s_barrier();
        __builtin_amdgcn_sched_barrier(0);

        cb = (cb == 2) ? 0 : cb + 1;
        sb = (sb == 2) ? 0 : sb + 1;
    }

    // epilogue: score[row] += sum_u tanh(P + t[b,u]) * V[u]
    float* fscore = (float*)sA;        // reuse LDS (vmcnt==0, all reads done)
    fscore[tid] = 0.f;
    __syncthreads();
    float tu[4], vu[4];
#pragma unroll
    for (int n = 0; n < 4; ++n) {
        int u = u0 + wn * 64 + n * 16 + l15;
        tu[n] = tvec[b * U_ + u];
        vu[n] = V[u];
    }
#pragma unroll
    for (int m = 0; m < 8; ++m) {
#pragma unroll
        for (int r = 0; r < 4; ++r) {
            float p = 0.f;
#pragma unroll
            for (int n = 0; n < 4; ++n) p += tanh_fast(acc[m][n][r] + tu[n]) * vu[n];
            p += __shfl_xor(p, 1);
            p += __shfl_xor(p, 2);
            p += __shfl_xor(p, 4);
            p += __shfl_xor(p, 8);
            if (l15 == 0) atomicAdd(&fscore[wm * 128 + m * 16 + lq * 4 + r], p);
        }
    }
    __syncthreads();
    atomicAdd(&scores[(size_t)b * S_ + s_local + tid], fscore[tid]);
}

// ---------------- K2 (legacy): MFMA scores GEMM, reg-staged (mid path) ------
template<bool ABF16>
__launch_bounds__(256, 2)
__global__ void scores_mfma(const void* __restrict__ aPtr,
                            const unsigned short* __restrict__ W1T,
                            const float* __restrict__ t,
                            const float* __restrict__ V,
                            float* __restrict__ scores) {
    __shared__ unsigned short sA[128 * 40];
    __shared__ unsigned short sB[256 * 40];
    __shared__ float fscore[128];

    const int tid  = threadIdx.x;
    const int lane = tid & 63;
    const int wave = tid >> 6;
    const int wm = wave & 1, wn = wave >> 1;
    const int l15 = lane & 15, lq = lane >> 4;

    const int id    = blockIdx.x;
    const int utile = (id >> 3) & 3;
    const int stile = (id & 7) | ((id >> 5) << 3);
    const size_t row0 = (size_t)stile * 128;
    const int b       = (int)(row0 >> 11);
    const int s_local = (int)(row0 & 2047);
    const int u0      = utile * 256;

    if (tid < 128) fscore[tid] = 0.f;

    const int ar = tid >> 1, ak = (tid & 1) << 4;
    const int br = tid >> 1, bk = (tid & 1) << 4;

    const float* Af = (const float*)aPtr + (row0 + ar) * 1024 + ak;
    const unsigned short* Ab = (const unsigned short*)aPtr + (row0 + ar) * 1024 + ak;
    const unsigned short* Bp0 = W1T + (size_t)(u0 + br) * 1024 + bk;
    const unsigned short* Bp1 = Bp0 + 128 * 1024;

    f32x4 acc[4][8];
#pragma unroll
    for (int i = 0; i < 4; ++i)
#pragma unroll
        for (int j = 0; j < 8; ++j) acc[i][j] = (f32x4)0.f;

    uint4 sa0, sa1, sb0, sb1, sb2, sb3;
    float4 fa0, fa1, fa2, fa3;

    if (ABF16) {
        sa0 = *(const uint4*)(Ab);
        sa1 = *(const uint4*)(Ab + 8);
    } else {
        fa0 = *(const float4*)(Af);
        fa1 = *(const float4*)(Af + 4);
        fa2 = *(const float4*)(Af + 8);
        fa3 = *(const float4*)(Af + 12);
    }
    sb0 = *(const uint4*)(Bp0);
    sb1 = *(const uint4*)(Bp0 + 8);
    sb2 = *(const uint4*)(Bp1);
    sb3 = *(const uint4*)(Bp1 + 8);

    for (int k0 = 0; k0 < 1024; k0 += 32) {
        __syncthreads();
        if (ABF16) {
            *(uint4*)&sA[ar * 40 + ak]     = sa0;
            *(uint4*)&sA[ar * 40 + ak + 8] = sa1;
        } else {
            union { unsigned short s[8]; uint4 u; } p0, p1;
            p0.s[0] = f2bf(fa0.x); p0.s[1] = f2bf(fa0.y); p0.s[2] = f2bf(fa0.z); p0.s[3] = f2bf(fa0.w);
            p0.s[4] = f2bf(fa1.x); p0.s[5] = f2bf(fa1.y); p0.s[6] = f2bf(fa1.z); p0.s[7] = f2bf(fa1.w);
            p1.s[0] = f2bf(fa2.x); p1.s[1] = f2bf(fa2.y); p1.s[2] = f2bf(fa2.z); p1.s[3] = f2bf(fa2.w);
            p1.s[4] = f2bf(fa3.x); p1.s[5] = f2bf(fa3.y); p1.s[6] = f2bf(fa3.z); p1.s[7] = f2bf(fa3.w);
            *(uint4*)&sA[ar * 40 + ak]     = p0.u;
            *(uint4*)&sA[ar * 40 + ak + 8] = p1.u;
        }
        *(uint4*)&sB[br * 40 + bk]           = sb0;
        *(uint4*)&sB[br * 40 + bk + 8]       = sb1;
        *(uint4*)&sB[(br + 128) * 40 + bk]     = sb2;
        *(uint4*)&sB[(br + 128) * 40 + bk + 8] = sb3;

        if (k0 + 32 < 1024) {
            int nk = k0 + 32;
            if (ABF16) {
                sa0 = *(const uint4*)(Ab + nk);
                sa1 = *(const uint4*)(Ab + nk + 8);
            } else {
                fa0 = *(const float4*)(Af + nk);
                fa1 = *(const float4*)(Af + nk + 4);
                fa2 = *(const float4*)(Af + nk + 8);
                fa3 = *(const float4*)(Af + nk + 12);
            }
            sb0 = *(const uint4*)(Bp0 + nk);
            sb1 = *(const uint4*)(Bp0 + nk + 8);
            sb2 = *(const uint4*)(Bp1 + nk);
            sb3 = *(const uint4*)(Bp1 + nk + 8);
        }
        __syncthreads();

        bf16x8 af[4];
#pragma unroll
        for (int i = 0; i < 4; ++i)
            af[i] = *(const bf16x8*)&sA[(64 * wm + 16 * i + l15) * 40 + lq * 8];
#pragma unroll
        for (int j = 0; j < 8; ++j) {
            bf16x8 bfj = *(const bf16x8*)&sB[(128 * wn + 16 * j + l15) * 40 + lq * 8];
#pragma unroll
            for (int i = 0; i < 4; ++i)
                acc[i][j] = __builtin_amdgcn_mfma_f32_16x16x32_bf16(af[i], bfj, acc[i][j], 0, 0, 0);
        }
    }

    float tu[8], vu[8];
#pragma unroll
    for (int j = 0; j < 8; ++j) {
        int u = u0 + 128 * wn + 16 * j + l15;
        tu[j] = t[b * U_ + u];
        vu[j] = V[u];
    }
#pragma unroll
    for (int i = 0; i < 4; ++i) {
#pragma unroll
        for (int r = 0; r < 4; ++r) {
            float p = 0.f;
#pragma unroll
            for (int j = 0; j < 8; ++j) p += tanh_fast(acc[i][j][r] + tu[j]) * vu[j];
            p += __shfl_xor(p, 1);
            p += __shfl_xor(p, 2);
            p += __shfl_xor(p, 4);
            p += __shfl_xor(p, 8);
            if (l15 == 0) atomicAdd(&fscore[64 * wm + 16 * i + lq * 4 + r], p);
        }
    }
    __syncthreads();
    if (tid < 128) atomicAdd(&scores[(size_t)b * S_ + s_local + tid], fscore[tid]);
}

// ---------------- K2-low: fp32 vector scores (last-resort ws fallback) ------
__launch_bounds__(256, 2)
__global__ void scores_vec(const float* __restrict__ values, const float* __restrict__ W1,
                           const float* __restrict__ t, const float* __restrict__ V,
                           float* __restrict__ scores) {
    __shared__ float vA[16][132];
    __shared__ float vB[16][68];
    __shared__ float fscore[128];
    const int b   = blockIdx.y;
    const int s0  = blockIdx.x * 128;
    const int tid = threadIdx.x;
    const int tx  = tid & 15, ty = tid >> 4;
    if (tid < 128) fscore[tid] = 0.f;
    const float* vbase = values + ((size_t)b * S_ + s0) * (size_t)DV;
    const int lm = tid >> 2, lkq = (tid & 3) * 4;
    const int lbk = tid >> 4, lbj = (tid & 15) * 4;
    for (int nt = 0; nt < U_ / 64; ++nt) {
        const int u0 = nt * 64;
        float acc[8][4];
#pragma unroll
        for (int i = 0; i < 8; ++i)
#pragma unroll
            for (int j = 0; j < 4; ++j) acc[i][j] = 0.f;
        for (int k0 = 0; k0 < DV; k0 += 16) {
            __syncthreads();
            const float4 v0 = *(const float4*)(vbase + (size_t)lm * DV + k0 + lkq);
            const float4 v1 = *(const float4*)(vbase + (size_t)(lm + 64) * DV + k0 + lkq);
            vA[lkq + 0][lm] = v0.x; vA[lkq + 1][lm] = v0.y;
            vA[lkq + 2][lm] = v0.z; vA[lkq + 3][lm] = v0.w;
            vA[lkq + 0][lm + 64] = v1.x; vA[lkq + 1][lm + 64] = v1.y;
            vA[lkq + 2][lm + 64] = v1.z; vA[lkq + 3][lm + 64] = v1.w;
            *(float4*)&vB[lbk][lbj] = *(const float4*)(W1 + (size_t)(k0 + lbk) * U_ + u0 + lbj);
            __syncthreads();
#pragma unroll
            for (int k = 0; k < 16; ++k) {
                float4 va0 = *(const float4*)&vA[k][ty * 8];
                float4 va1 = *(const float4*)&vA[k][ty * 8 + 4];
                float4 vb  = *(const float4*)&vB[k][tx * 4];
                float a_[8] = {va0.x, va0.y, va0.z, va0.w, va1.x, va1.y, va1.z, va1.w};
                float b_[4] = {vb.x, vb.y, vb.z, vb.w};
#pragma unroll
                for (int i = 0; i < 8; ++i)
#pragma unroll
                    for (int j = 0; j < 4; ++j) acc[i][j] += a_[i] * b_[j];
            }
        }
        float tq[4], vv[4];
#pragma unroll
        for (int j = 0; j < 4; ++j) {
            int u = u0 + tx * 4 + j;
            tq[j] = t[b * U_ + u];
            vv[j] = V[u];
        }
#pragma unroll
        for (int i = 0; i < 8; ++i) {
            float p = 0.f;
#pragma unroll
            for (int j = 0; j < 4; ++j) p += tanhf(acc[i][j] + tq[j]) * vv[j];
            p += __shfl_down(p, 8, 16);
            p += __shfl_down(p, 4, 16);
            p += __shfl_down(p, 2, 16);
            p += __shfl_down(p, 1, 16);
            if (tx == 0) fscore[ty * 8 + i] += p;
        }
    }
    __syncthreads();
    if (tid < 128) scores[(size_t)b * S_ + s0 + tid] = fscore[tid];
}

// ---------------- K3: softmax over S per batch ------------------------------
__global__ void softmax_kernel(const float* __restrict__ scores, float* __restrict__ wout) {
    int b = blockIdx.x;
    int tid = threadIdx.x;
    __shared__ float red[256];
    float v[8];
    float m = -1e30f;
#pragma unroll
    for (int i = 0; i < 8; ++i) {
        v[i] = scores[(size_t)b * S_ + tid + i * 256];
        m = fmaxf(m, v[i]);
    }
    red[tid] = m; __syncthreads();
    for (int off = 128; off > 0; off >>= 1) {
        if (tid < off) red[tid] = fmaxf(red[tid], red[tid + off]);
        __syncthreads();
    }
    m = red[0];
    __syncthreads();
    float s = 0.f;
#pragma unroll
    for (int i = 0; i < 8; ++i) { v[i] = __expf(v[i] - m); s += v[i]; }
    red[tid] = s; __syncthreads();
    for (int off = 128; off > 0; off >>= 1) {
        if (tid < off) red[tid] += red[tid + off];
        __syncthreads();
    }
    float inv = 1.f / red[0];
#pragma unroll
    for (int i = 0; i < 8; ++i) wout[(size_t)b * S_ + tid + i * 256] = v[i] * inv;
}

// ---------------- K4: context[b,d] = sum_s w[b,s] * values[b,s,d] -----------
__global__ void context_kernel(const float* __restrict__ values, const float* __restrict__ w,
                               float* __restrict__ ctx) {
    int b  = blockIdx.x;
    int dc = blockIdx.y;
    int sc = blockIdx.z;
    int tid = threadIdx.x;
    int d = dc * 256 + tid;
    __shared__ float ws_[256];
    ws_[tid] = w[(size_t)b * S_ + sc * 256 + tid];
    __syncthreads();
    float acc = 0.f;
    const float* vp = values + ((size_t)b * S_ + sc * 256) * (size_t)DV + d;
#pragma unroll 4
    for (int s = 0; s < 256; ++s) acc += ws_[s] * vp[(size_t)s * DV];
    atomicAdd(&ctx[b * DV + d], acc);
}

// ---------------- launch ----------------------------------------------------
extern "C" void kernel_launch(void* const* d_in, const int* in_sizes, int n_in,
                              void* d_out, int out_size, void* d_ws, size_t ws_size,
                              hipStream_t stream) {
    const float* query  = (const float*)d_in[0];
    const float* values = (const float*)d_in[1];
    const float* W1     = (const float*)d_in[2];
    const float* b1     = (const float*)d_in[3];
    const float* W2     = (const float*)d_in[4];
    const float* b2     = (const float*)d_in[5];
    const float* V      = (const float*)d_in[6];
    // bV (d_in[7]) shifts all scores equally -> softmax-invariant.

    float* out  = (float*)d_out;
    float* ctx  = out;                 // [32, 1024]
    float* wout = out + B_ * DV;       // [32, 2048]

    char* ws = (char*)d_ws;
    const size_t W1T_BYTES = (size_t)U_ * DV * 2;              // 2 MB
    const size_t T_BYTES   = (size_t)B_ * U_ * 4;              // 128 KB
    const size_t SC_BYTES  = (size_t)B_ * S_ * 4;              // 256 KB
    const size_t ABF_BYTES = (size_t)B_ * S_ * DV * 2;         // 128 MB

    if (ws_size >= W1T_BYTES + T_BYTES + SC_BYTES + ABF_BYTES) {
        // fast path: bf16 A + bf16 W1T, counted-vmcnt 3-buffer MFMA
        unsigned short* W1T = (unsigned short*)ws;
        float* t      = (float*)(ws + W1T_BYTES);
        float* scores = t + B_ * U_;
        unsigned short* Abf = (unsigned short*)(scores + B_ * S_);

        init_kernel   <<<dim3(256),      256, 0, stream>>>(b1, b2, t, ctx, scores);
        projq_kernel  <<<dim3(32, 16),   256, 0, stream>>>(query, W2, t);
        cvt_values    <<<dim3(32768),    256, 0, stream>>>(values, Abf);
        prep_w1t      <<<dim3(16, 16),   256, 0, stream>>>(W1, W1T);
        scores_mfma3  <<<dim3(2048),     256, 0, stream>>>(Abf, W1T, t, V, scores);
        softmax_kernel<<<dim3(32),       256, 0, stream>>>(scores, wout);
        context_kernel<<<dim3(32, 4, 8), 256, 0, stream>>>(values, wout, ctx);
    } else if (ws_size >= W1T_BYTES + T_BYTES + SC_BYTES) {
        // mid path: fp32 A converted in-kernel, bf16 W1T, MFMA
        unsigned short* W1T = (unsigned short*)ws;
        float* t      = (float*)(ws + W1T_BYTES);
        float* scores = t + B_ * U_;

        init_kernel   <<<dim3(256),      256, 0, stream>>>(b1, b2, t, ctx, scores);
        projq_kernel  <<<dim3(32, 16),   256, 0, stream>>>(query, W2, t);
        prep_w1t      <<<dim3(16, 16),   256, 0, stream>>>(W1, W1T);
        scores_mfma<false><<<dim3(2048), 256, 0, stream>>>(values, W1T, t, V, scores);
        softmax_kernel<<<dim3(32),       256, 0, stream>>>(scores, wout);
        context_kernel<<<dim3(32, 4, 8), 256, 0, stream>>>(values, wout, ctx);
    } else {
        // low path: round-1 fp32 vector kernel (384 KB ws, proven)
        float* t      = (float*)ws;
        float* scores = t + B_ * U_;

        init_kernel   <<<dim3(256),      256, 0, stream>>>(b1, b2, t, ctx, scores);
        projq_kernel  <<<dim3(32, 16),   256, 0, stream>>>(query, W2, t);
        scores_vec    <<<dim3(16, 32),   256, 0, stream>>>(values, W1, t, V, scores);
        softmax_kernel<<<dim3(32),       256, 0, stream>>>(scores, wout);
        context_kernel<<<dim3(32, 4, 8), 256, 0, stream>>>(values, wout, ctx);
    }
}

// Round 3
// 597.800 us; speedup vs baseline: 1.0788x; 1.0618x over previous
//
#include <hip/hip_runtime.h>
#include <math.h>

#define B_  32
#define S_  2048
#define DV  1024
#define U_  1024

typedef __attribute__((ext_vector_type(8))) short bf16x8;
typedef __attribute__((ext_vector_type(4))) float f32x4;

__device__ inline unsigned short f2bf(float f) {
    unsigned int x = __float_as_uint(f);
    return (unsigned short)((x + 0x7fffu + ((x >> 16) & 1u)) >> 16);
}

__device__ inline float tanh_fast(float x) {
    float ax = fabsf(x);
    float e  = __expf(ax + ax);
    float t  = 1.0f - __fdividef(2.0f, e + 1.0f);
    return copysignf(t, x);
}

// async global->LDS, 16B per lane; LDS dest is the wave-uniform base
// (HW adds lane*16 itself). Global ptr is per-lane.
__device__ __forceinline__ void gload16(const void* g, void* l) {
    __builtin_amdgcn_global_load_lds(
        (const __attribute__((address_space(1))) void*)g,
        (__attribute__((address_space(3))) void*)l,
        16, 0, 0);
}

#define ASM_VMCNT(N) asm volatile("s_waitcnt vmcnt(" #N ")" ::: "memory")
#define ASM_LGKM0()  do { asm volatile("s_waitcnt lgkmcnt(0)" ::: "memory"); \
                          __builtin_amdgcn_sched_barrier(0); } while (0)

// ---------------- K0: t[b,u] = b1[u]+b2[u]; zero ctx + scores ---------------
__global__ void init_kernel(const float* __restrict__ b1, const float* __restrict__ b2,
                            float* __restrict__ t, float* __restrict__ ctx,
                            float* __restrict__ scores) {
    int i = blockIdx.x * 256 + threadIdx.x;   // 65536
    scores[i] = 0.f;
    if (i < B_ * U_) {
        int u = i & (U_ - 1);
        t[i]   = b1[u] + b2[u];
        ctx[i] = 0.f;
    }
}

// ---------------- K1: t[b,u] += query[b,:] @ W2[:,u] ------------------------
__global__ void projq_kernel(const float* __restrict__ q, const float* __restrict__ W2,
                             float* __restrict__ t) {
    int b  = blockIdx.x;        // 32
    int ks = blockIdx.y;        // 16 chunks of 64 k-rows
    int tid = threadIdx.x;
    __shared__ float qs[64];
    if (tid < 64) qs[tid] = q[b * DV + ks * 64 + tid];
    __syncthreads();
    float a0 = 0.f, a1 = 0.f, a2 = 0.f, a3 = 0.f;
    const float* w = W2 + (size_t)(ks * 64) * U_;
    for (int d = 0; d < 64; ++d) {
        float qd = qs[d];
        const float* wr = w + (size_t)d * U_ + tid;
        a0 += qd * wr[0];
        a1 += qd * wr[256];
        a2 += qd * wr[512];
        a3 += qd * wr[768];
    }
    atomicAdd(&t[b * U_ + tid      ], a0);
    atomicAdd(&t[b * U_ + tid + 256], a1);
    atomicAdd(&t[b * U_ + tid + 512], a2);
    atomicAdd(&t[b * U_ + tid + 768], a3);
}

// ---------------- prep: values fp32 -> bf16 ---------------------------------
__global__ void cvt_values(const float* __restrict__ v, unsigned short* __restrict__ o) {
    size_t i = ((size_t)blockIdx.x * 256 + threadIdx.x) * 8;
    float4 f0 = *(const float4*)(v + i);
    float4 f1 = *(const float4*)(v + i + 4);
    union { unsigned short s[8]; uint4 u; } p;
    p.s[0] = f2bf(f0.x); p.s[1] = f2bf(f0.y); p.s[2] = f2bf(f0.z); p.s[3] = f2bf(f0.w);
    p.s[4] = f2bf(f1.x); p.s[5] = f2bf(f1.y); p.s[6] = f2bf(f1.z); p.s[7] = f2bf(f1.w);
    *(uint4*)(o + i) = p.u;
}

// ---------------- prep: W1 [k][u] fp32 -> W1T [u][k] bf16 -------------------
__global__ void prep_w1t(const float* __restrict__ W1, unsigned short* __restrict__ W1T) {
    __shared__ float tile[64][65];
    int k0 = blockIdx.x * 64, u0 = blockIdx.y * 64;
    int t = threadIdx.x;
    int lr = t >> 4, lc = (t & 15) * 4;
#pragma unroll
    for (int i = 0; i < 4; ++i) {
        float4 f = *(const float4*)&W1[(size_t)(k0 + lr + i * 16) * U_ + u0 + lc];
        tile[lr + i * 16][lc + 0] = f.x; tile[lr + i * 16][lc + 1] = f.y;
        tile[lr + i * 16][lc + 2] = f.z; tile[lr + i * 16][lc + 3] = f.w;
    }
    __syncthreads();
    int ur = t >> 2, kq = (t & 3) * 16;
    union { unsigned short s[8]; uint4 u; } p0, p1;
#pragma unroll
    for (int e = 0; e < 8; ++e) p0.s[e] = f2bf(tile[kq + e][ur]);
#pragma unroll
    for (int e = 0; e < 8; ++e) p1.s[e] = f2bf(tile[kq + 8 + e][ur]);
    unsigned short* dst = W1T + (size_t)(u0 + ur) * 1024 + k0 + kq;
    *(uint4*)dst       = p0.u;
    *(uint4*)(dst + 8) = p1.u;
}

// ---------------- K2 v4: 256x256 tile, BK=64, 8-phase schedule (m201 port) --
// 512 thr = 8 waves (2M x 4N), wave tile 128x64, acc 8x4 f32x4 (128 VGPR).
// LDS 128 KB: dbuf d in {0,1} x {A,B} x 2 halves of [128 rows][64 k] bf16.
// Layout: byte = row*128 + pchunk*16, pchunk = (k>>3) ^ (row & 7)  (m214 XOR).
// global_load_lds writes linearly -> inverse-XOR'd global source per lane.
// Iteration it: phases 0-3 compute K-tile 2it (dbuf0), 4-7 compute 2it+1
// (dbuf1). Quadrant phases: ph0 m0-3 x n0-1 (12 ds_read), ph1 m0-3 x n2-3 (4),
// ph2 m4-7 x n2-3 (8), ph3 m4-7 x n0-1 (4); each x both 32-k slices = 16 MFMA.
// Staging ring (1 half-tile = 2 gload16/wave per phase):
//   ph0: A1(kt1)->d1  ph1: B0(kt1)->d1  ph2: B1(kt1)->d1
//   ph3: A0(kt2)->d0  ph4: A1(kt2)->d0  ph5: B0(kt2)->d0  ph6: B1(kt2)->d0
//   ph7: A0(kt3)->d1          (ph3-7 only while a next tile exists)
// Liveness: A(d) last read at 2nd a-phase, B(d) at 4th b-phase; every stage
// targets a region whose last ds_read was drained >=1 barrier earlier.
// vmcnt: end-ph3 vmcnt(2) (retires d1's 8 loads, leaves ph3's 2 in flight);
// end-ph7 vmcnt(2) (retires d0's, leaves ph7's). Never 0 until the last tile.
#define MFMA16(MB, NB)                                                          \
    _Pragma("unroll") for (int ks = 0; ks < 2; ++ks)                            \
    _Pragma("unroll") for (int n = 0; n < 2; ++n)                               \
    _Pragma("unroll") for (int m = 0; m < 4; ++m)                               \
        acc[(MB)+m][(NB)+n] = __builtin_amdgcn_mfma_f32_16x16x32_bf16(          \
            af[m][ks], bf[n][ks], acc[(MB)+m][(NB)+n], 0, 0, 0);

__launch_bounds__(512, 2)
__global__ void scores_mfma8(const unsigned short* __restrict__ Abf,
                             const unsigned short* __restrict__ W1T,
                             const float* __restrict__ tvec,
                             const float* __restrict__ V,
                             float* __restrict__ scores) {
    __shared__ __align__(16) char lds[131072];   // 128 KB

    const int tid  = threadIdx.x;
    const int lane = tid & 63;
    const int wave = tid >> 6;        // 0..7
    const int wm   = wave >> 2;       // 0..1  (row half of 256)
    const int wn   = wave & 3;        // 0..3  (64-col strip of 256)
    const int l15  = lane & 15;
    const int lq   = lane >> 4;       // 0..3

    // XCD-chunked swizzle: 1024 blocks, XCD x owns a contiguous 128-block span;
    // utile-neighbors (sharing an A-strip) stay on one XCD's L2.
    const int id    = blockIdx.x;
    const int wg    = (id & 7) * 128 + (id >> 3);
    const int utile = wg & 3;                    // 4 u-tiles of 256
    const int stile = wg >> 2;                   // 256 s-tiles of 256
    const size_t row0 = (size_t)stile * 256;
    const int b       = (int)(row0 >> 11);
    const int s_local = (int)(row0 & 2047);
    const int u0      = utile * 256;

    // ---- staging lane constants: linear LDS dest, inverse-XOR global src
    // thread covers LDS bytes [ro*8192 + wave*1024 + lane*16):  row = ro*64 +
    // wave*8 + (lane>>3), pchunk = lane&7  ->  logical kchunk = pchunk^(row&7).
    const int rowst = wave * 8 + (lane >> 3);
    const int kch8  = ((lane & 7) ^ ((lane >> 3) & 7)) * 8;
    const unsigned short* aSrc = Abf + (row0 + rowst) * 1024 + kch8;
    const unsigned short* bSrc = W1T + (size_t)(u0 + rowst) * 1024 + kch8;
    char* const dstW = lds + wave * 1024;        // wave-uniform base part

    // ---- fragment read lane offsets (bytes). pchunk(ks=1) = pchunk(ks=0)^4
    // -> byte offset XOR 64.
    const int ao0 = wm * 16384 + l15 * 128 + ((lq ^ (l15 & 7)) << 4);
    const int ao1 = ao0 ^ 64;
    const int bo0 = 32768 + (wn >> 1) * 16384 + (wn & 1) * 8192
                  + l15 * 128 + ((lq ^ (l15 & 7)) << 4);
    const int bo1 = bo0 ^ 64;

    f32x4 acc[8][4];
#pragma unroll
    for (int m = 0; m < 8; ++m)
#pragma unroll
        for (int n = 0; n < 4; ++n) acc[m][n] = (f32x4)0.f;

    bf16x8 af[4][2];
    bf16x8 bf[2][2];

    auto stage2 = [&](const unsigned short* s, int dOff) {
        gload16(s,             dstW + dOff);
        gload16(s + 64 * 1024, dstW + dOff + 8192);
    };
    auto readA4 = [&](int base) {   // base = d*65536 + mb*2048
#pragma unroll
        for (int m = 0; m < 4; ++m) {
            af[m][0] = *(const bf16x8*)(lds + base + m * 2048 + ao0);
            af[m][1] = *(const bf16x8*)(lds + base + m * 2048 + ao1);
        }
    };
    auto readB2 = [&](int base) {   // base = d*65536 + nb*2048
#pragma unroll
        for (int n = 0; n < 2; ++n) {
            bf[n][0] = *(const bf16x8*)(lds + base + n * 2048 + bo0);
            bf[n][1] = *(const bf16x8*)(lds + base + n * 2048 + bo1);
        }
    };

    // LDS region offsets: OFF(d,mat,h) = d*65536 + mat*32768 + h*16384
    // prologue: kt0 -> d0 (4 halves), A0(kt1) -> d1
    stage2(aSrc,          0);
    stage2(aSrc + 131072, 16384);
    stage2(bSrc,          32768);
    stage2(bSrc + 131072, 49152);
    stage2(aSrc + 64,     65536);
    __builtin_amdgcn_sched_barrier(0);
    ASM_VMCNT(2);                       // kt0 (8 loads) landed; d1A0 in flight
    __builtin_amdgcn_s_barrier();
    __builtin_amdgcn_sched_barrier(0);

    for (int it = 0; it < 8; ++it) {
        const bool pf = (it < 7);
        // ---------- phase 0: d0, m0-3 x n0-1 ----------
        readA4(0);
        readB2(0);
        stage2(aSrc + 64 + 131072, 81920);           // A1(kt1) -> d1
        __builtin_amdgcn_s_barrier();
        ASM_LGKM0();
        __builtin_amdgcn_s_setprio(1);
        MFMA16(0, 0);
        __builtin_amdgcn_s_setprio(0);
        __builtin_amdgcn_s_barrier();
        // ---------- phase 1: d0, m0-3 x n2-3 ----------
        readB2(2 * 2048);
        stage2(bSrc + 64, 98304);                    // B0(kt1) -> d1
        __builtin_amdgcn_s_barrier();
        ASM_LGKM0();
        __builtin_amdgcn_s_setprio(1);
        MFMA16(0, 2);
        __builtin_amdgcn_s_setprio(0);
        __builtin_amdgcn_s_barrier();
        // ---------- phase 2: d0, m4-7 x n2-3 ----------
        readA4(4 * 2048);
        stage2(bSrc + 64 + 131072, 114688);          // B1(kt1) -> d1
        __builtin_amdgcn_s_barrier();
        ASM_LGKM0();
        __builtin_amdgcn_s_setprio(1);
        MFMA16(4, 2);
        __builtin_amdgcn_s_setprio(0);
        __builtin_amdgcn_s_barrier();
        // ---------- phase 3: d0, m4-7 x n0-1 ----------
        readB2(0);
        if (pf) stage2(aSrc + 128, 0);               // A0(kt2) -> d0
        __builtin_amdgcn_s_barrier();
        ASM_LGKM0();
        __builtin_amdgcn_s_setprio(1);
        MFMA16(4, 0);
        __builtin_amdgcn_s_setprio(0);
        __builtin_amdgcn_sched_barrier(0);
        if (pf) { ASM_VMCNT(2); } else { ASM_VMCNT(0); }   // d1 (kt1) landed
        __builtin_amdgcn_s_barrier();
        __builtin_amdgcn_sched_barrier(0);
        // ---------- phase 4: d1, m0-3 x n0-1 ----------
        readA4(65536);
        readB2(65536);
        if (pf) stage2(aSrc + 128 + 131072, 16384);  // A1(kt2) -> d0
        __builtin_amdgcn_s_barrier();
        ASM_LGKM0();
        __builtin_amdgcn_s_setprio(1);
        MFMA16(0, 0);
        __builtin_amdgcn_s_setprio(0);
        __builtin_amdgcn_s_barrier();
        // ---------- phase 5: d1, m0-3 x n2-3 ----------
        readB2(65536 + 2 * 2048);
        if (pf) stage2(bSrc + 128, 32768);           // B0(kt2) -> d0
        __builtin_amdgcn_s_barrier();
        ASM_LGKM0();
        __builtin_amdgcn_s_setprio(1);
        MFMA16(0, 2);
        __builtin_amdgcn_s_setprio(0);
        __builtin_amdgcn_s_barrier();
        // ---------- phase 6: d1, m4-7 x n2-3 ----------
        readA4(65536 + 4 * 2048);
        if (pf) stage2(bSrc + 128 + 131072, 49152);  // B1(kt2) -> d0
        __builtin_amdgcn_s_barrier();
        ASM_LGKM0();
        __builtin_amdgcn_s_setprio(1);
        MFMA16(4, 2);
        __builtin_amdgcn_s_setprio(0);
        __builtin_amdgcn_s_barrier();
        // ---------- phase 7: d1, m4-7 x n0-1 ----------
        readB2(65536);
        if (pf) stage2(aSrc + 192, 65536);           // A0(kt3) -> d1
        __builtin_amdgcn_s_barrier();
        ASM_LGKM0();
        __builtin_amdgcn_s_setprio(1);
        MFMA16(4, 0);
        __builtin_amdgcn_s_setprio(0);
        __builtin_amdgcn_sched_barrier(0);
        if (pf) { ASM_VMCNT(2); }                    // d0 (kt2) landed
        __builtin_amdgcn_s_barrier();
        __builtin_amdgcn_sched_barrier(0);

        aSrc += 128;
        bSrc += 128;
    }

    // epilogue: score[row] += sum_u tanh(P + t[b,u]) * V[u]
    __syncthreads();
    float* fscore = (float*)lds;
    if (tid < 256) fscore[tid] = 0.f;
    __syncthreads();
    float tu[4], vu[4];
#pragma unroll
    for (int n = 0; n < 4; ++n) {
        int u = u0 + wn * 64 + n * 16 + l15;
        tu[n] = tvec[b * U_ + u];
        vu[n] = V[u];
    }
#pragma unroll
    for (int m = 0; m < 8; ++m) {
#pragma unroll
        for (int r = 0; r < 4; ++r) {
            float p = 0.f;
#pragma unroll
            for (int n = 0; n < 4; ++n) p += tanh_fast(acc[m][n][r] + tu[n]) * vu[n];
            p += __shfl_xor(p, 1);
            p += __shfl_xor(p, 2);
            p += __shfl_xor(p, 4);
            p += __shfl_xor(p, 8);
            if (l15 == 0) atomicAdd(&fscore[wm * 128 + m * 16 + lq * 4 + r], p);
        }
    }
    __syncthreads();
    if (tid < 256) atomicAdd(&scores[(size_t)b * S_ + s_local + tid], fscore[tid]);
}

// ---------------- K2 (legacy): MFMA scores GEMM, reg-staged (mid path) ------
template<bool ABF16>
__launch_bounds__(256, 2)
__global__ void scores_mfma(const void* __restrict__ aPtr,
                            const unsigned short* __restrict__ W1T,
                            const float* __restrict__ t,
                            const float* __restrict__ V,
                            float* __restrict__ scores) {
    __shared__ unsigned short sA[128 * 40];
    __shared__ unsigned short sB[256 * 40];
    __shared__ float fscore[128];

    const int tid  = threadIdx.x;
    const int lane = tid & 63;
    const int wave = tid >> 6;
    const int wm = wave & 1, wn = wave >> 1;
    const int l15 = lane & 15, lq = lane >> 4;

    const int id    = blockIdx.x;
    const int utile = (id >> 3) & 3;
    const int stile = (id & 7) | ((id >> 5) << 3);
    const size_t row0 = (size_t)stile * 128;
    const int b       = (int)(row0 >> 11);
    const int s_local = (int)(row0 & 2047);
    const int u0      = utile * 256;

    if (tid < 128) fscore[tid] = 0.f;

    const int ar = tid >> 1, ak = (tid & 1) << 4;
    const int br = tid >> 1, bk = (tid & 1) << 4;

    const float* Af = (const float*)aPtr + (row0 + ar) * 1024 + ak;
    const unsigned short* Ab = (const unsigned short*)aPtr + (row0 + ar) * 1024 + ak;
    const unsigned short* Bp0 = W1T + (size_t)(u0 + br) * 1024 + bk;
    const unsigned short* Bp1 = Bp0 + 128 * 1024;

    f32x4 acc[4][8];
#pragma unroll
    for (int i = 0; i < 4; ++i)
#pragma unroll
        for (int j = 0; j < 8; ++j) acc[i][j] = (f32x4)0.f;

    uint4 sa0, sa1, sb0, sb1, sb2, sb3;
    float4 fa0, fa1, fa2, fa3;

    if (ABF16) {
        sa0 = *(const uint4*)(Ab);
        sa1 = *(const uint4*)(Ab + 8);
    } else {
        fa0 = *(const float4*)(Af);
        fa1 = *(const float4*)(Af + 4);
        fa2 = *(const float4*)(Af + 8);
        fa3 = *(const float4*)(Af + 12);
    }
    sb0 = *(const uint4*)(Bp0);
    sb1 = *(const uint4*)(Bp0 + 8);
    sb2 = *(const uint4*)(Bp1);
    sb3 = *(const uint4*)(Bp1 + 8);

    for (int k0 = 0; k0 < 1024; k0 += 32) {
        __syncthreads();
        if (ABF16) {
            *(uint4*)&sA[ar * 40 + ak]     = sa0;
            *(uint4*)&sA[ar * 40 + ak + 8] = sa1;
        } else {
            union { unsigned short s[8]; uint4 u; } p0, p1;
            p0.s[0] = f2bf(fa0.x); p0.s[1] = f2bf(fa0.y); p0.s[2] = f2bf(fa0.z); p0.s[3] = f2bf(fa0.w);
            p0.s[4] = f2bf(fa1.x); p0.s[5] = f2bf(fa1.y); p0.s[6] = f2bf(fa1.z); p0.s[7] = f2bf(fa1.w);
            p1.s[0] = f2bf(fa2.x); p1.s[1] = f2bf(fa2.y); p1.s[2] = f2bf(fa2.z); p1.s[3] = f2bf(fa2.w);
            p1.s[4] = f2bf(fa3.x); p1.s[5] = f2bf(fa3.y); p1.s[6] = f2bf(fa3.z); p1.s[7] = f2bf(fa3.w);
            *(uint4*)&sA[ar * 40 + ak]     = p0.u;
            *(uint4*)&sA[ar * 40 + ak + 8] = p1.u;
        }
        *(uint4*)&sB[br * 40 + bk]           = sb0;
        *(uint4*)&sB[br * 40 + bk + 8]       = sb1;
        *(uint4*)&sB[(br + 128) * 40 + bk]     = sb2;
        *(uint4*)&sB[(br + 128) * 40 + bk + 8] = sb3;

        if (k0 + 32 < 1024) {
            int nk = k0 + 32;
            if (ABF16) {
                sa0 = *(const uint4*)(Ab + nk);
                sa1 = *(const uint4*)(Ab + nk + 8);
            } else {
                fa0 = *(const float4*)(Af + nk);
                fa1 = *(const float4*)(Af + nk + 4);
                fa2 = *(const float4*)(Af + nk + 8);
                fa3 = *(const float4*)(Af + nk + 12);
            }
            sb0 = *(const uint4*)(Bp0 + nk);
            sb1 = *(const uint4*)(Bp0 + nk + 8);
            sb2 = *(const uint4*)(Bp1 + nk);
            sb3 = *(const uint4*)(Bp1 + nk + 8);
        }
        __syncthreads();

        bf16x8 af[4];
#pragma unroll
        for (int i = 0; i < 4; ++i)
            af[i] = *(const bf16x8*)&sA[(64 * wm + 16 * i + l15) * 40 + lq * 8];
#pragma unroll
        for (int j = 0; j < 8; ++j) {
            bf16x8 bfj = *(const bf16x8*)&sB[(128 * wn + 16 * j + l15) * 40 + lq * 8];
#pragma unroll
            for (int i = 0; i < 4; ++i)
                acc[i][j] = __builtin_amdgcn_mfma_f32_16x16x32_bf16(af[i], bfj, acc[i][j], 0, 0, 0);
        }
    }

    float tu[8], vu[8];
#pragma unroll
    for (int j = 0; j < 8; ++j) {
        int u = u0 + 128 * wn + 16 * j + l15;
        tu[j] = t[b * U_ + u];
        vu[j] = V[u];
    }
#pragma unroll
    for (int i = 0; i < 4; ++i) {
#pragma unroll
        for (int r = 0; r < 4; ++r) {
            float p = 0.f;
#pragma unroll
            for (int j = 0; j < 8; ++j) p += tanh_fast(acc[i][j][r] + tu[j]) * vu[j];
            p += __shfl_xor(p, 1);
            p += __shfl_xor(p, 2);
            p += __shfl_xor(p, 4);
            p += __shfl_xor(p, 8);
            if (l15 == 0) atomicAdd(&fscore[64 * wm + 16 * i + lq * 4 + r], p);
        }
    }
    __syncthreads();
    if (tid < 128) atomicAdd(&scores[(size_t)b * S_ + s_local + tid], fscore[tid]);
}

// ---------------- K2-low: fp32 vector scores (last-resort ws fallback) ------
__launch_bounds__(256, 2)
__global__ void scores_vec(const float* __restrict__ values, const float* __restrict__ W1,
                           const float* __restrict__ t, const float* __restrict__ V,
                           float* __restrict__ scores) {
    __shared__ float vA[16][132];
    __shared__ float vB[16][68];
    __shared__ float fscore[128];
    const int b   = blockIdx.y;
    const int s0  = blockIdx.x * 128;
    const int tid = threadIdx.x;
    const int tx  = tid & 15, ty = tid >> 4;
    if (tid < 128) fscore[tid] = 0.f;
    const float* vbase = values + ((size_t)b * S_ + s0) * (size_t)DV;
    const int lm = tid >> 2, lkq = (tid & 3) * 4;
    const int lbk = tid >> 4, lbj = (tid & 15) * 4;
    for (int nt = 0; nt < U_ / 64; ++nt) {
        const int u0 = nt * 64;
        float acc[8][4];
#pragma unroll
        for (int i = 0; i < 8; ++i)
#pragma unroll
            for (int j = 0; j < 4; ++j) acc[i][j] = 0.f;
        for (int k0 = 0; k0 < DV; k0 += 16) {
            __syncthreads();
            const float4 v0 = *(const float4*)(vbase + (size_t)lm * DV + k0 + lkq);
            const float4 v1 = *(const float4*)(vbase + (size_t)(lm + 64) * DV + k0 + lkq);
            vA[lkq + 0][lm] = v0.x; vA[lkq + 1][lm] = v0.y;
            vA[lkq + 2][lm] = v0.z; vA[lkq + 3][lm] = v0.w;
            vA[lkq + 0][lm + 64] = v1.x; vA[lkq + 1][lm + 64] = v1.y;
            vA[lkq + 2][lm + 64] = v1.z; vA[lkq + 3][lm + 64] = v1.w;
            *(float4*)&vB[lbk][lbj] = *(const float4*)(W1 + (size_t)(k0 + lbk) * U_ + u0 + lbj);
            __syncthreads();
#pragma unroll
            for (int k = 0; k < 16; ++k) {
                float4 va0 = *(const float4*)&vA[k][ty * 8];
                float4 va1 = *(const float4*)&vA[k][ty * 8 + 4];
                float4 vb  = *(const float4*)&vB[k][tx * 4];
                float a_[8] = {va0.x, va0.y, va0.z, va0.w, va1.x, va1.y, va1.z, va1.w};
                float b_[4] = {vb.x, vb.y, vb.z, vb.w};
#pragma unroll
                for (int i = 0; i < 8; ++i)
#pragma unroll
                    for (int j = 0; j < 4; ++j) acc[i][j] += a_[i] * b_[j];
            }
        }
        float tq[4], vv[4];
#pragma unroll
        for (int j = 0; j < 4; ++j) {
            int u = u0 + tx * 4 + j;
            tq[j] = t[b * U_ + u];
            vv[j] = V[u];
        }
#pragma unroll
        for (int i = 0; i < 8; ++i) {
            float p = 0.f;
#pragma unroll
            for (int j = 0; j < 4; ++j) p += tanhf(acc[i][j] + tq[j]) * vv[j];
            p += __shfl_down(p, 8, 16);
            p += __shfl_down(p, 4, 16);
            p += __shfl_down(p, 2, 16);
            p += __shfl_down(p, 1, 16);
            if (tx == 0) fscore[ty * 8 + i] += p;
        }
    }
    __syncthreads();
    if (tid < 128) scores[(size_t)b * S_ + s0 + tid] = fscore[tid];
}

// ---------------- K3: softmax over S per batch ------------------------------
__global__ void softmax_kernel(const float* __restrict__ scores, float* __restrict__ wout) {
    int b = blockIdx.x;
    int tid = threadIdx.x;
    __shared__ float red[256];
    float v[8];
    float m = -1e30f;
#pragma unroll
    for (int i = 0; i < 8; ++i) {
        v[i] = scores[(size_t)b * S_ + tid + i * 256];
        m = fmaxf(m, v[i]);
    }
    red[tid] = m; __syncthreads();
    for (int off = 128; off > 0; off >>= 1) {
        if (tid < off) red[tid] = fmaxf(red[tid], red[tid + off]);
        __syncthreads();
    }
    m = red[0];
    __syncthreads();
    float s = 0.f;
#pragma unroll
    for (int i = 0; i < 8; ++i) { v[i] = __expf(v[i] - m); s += v[i]; }
    red[tid] = s; __syncthreads();
    for (int off = 128; off > 0; off >>= 1) {
        if (tid < off) red[tid] += red[tid + off];
        __syncthreads();
    }
    float inv = 1.f / red[0];
#pragma unroll
    for (int i = 0; i < 8; ++i) wout[(size_t)b * S_ + tid + i * 256] = v[i] * inv;
}

// ---------------- K4: context[b,d] = sum_s w[b,s] * values[b,s,d] -----------
__global__ void context_kernel(const float* __restrict__ values, const float* __restrict__ w,
                               float* __restrict__ ctx) {
    int b  = blockIdx.x;
    int dc = blockIdx.y;
    int sc = blockIdx.z;
    int tid = threadIdx.x;
    int d = dc * 256 + tid;
    __shared__ float ws_[256];
    ws_[tid] = w[(size_t)b * S_ + sc * 256 + tid];
    __syncthreads();
    float acc = 0.f;
    const float* vp = values + ((size_t)b * S_ + sc * 256) * (size_t)DV + d;
#pragma unroll 4
    for (int s = 0; s < 256; ++s) acc += ws_[s] * vp[(size_t)s * DV];
    atomicAdd(&ctx[b * DV + d], acc);
}

// ---------------- launch ----------------------------------------------------
extern "C" void kernel_launch(void* const* d_in, const int* in_sizes, int n_in,
                              void* d_out, int out_size, void* d_ws, size_t ws_size,
                              hipStream_t stream) {
    const float* query  = (const float*)d_in[0];
    const float* values = (const float*)d_in[1];
    const float* W1     = (const float*)d_in[2];
    const float* b1     = (const float*)d_in[3];
    const float* W2     = (const float*)d_in[4];
    const float* b2     = (const float*)d_in[5];
    const float* V      = (const float*)d_in[6];
    // bV (d_in[7]) shifts all scores equally -> softmax-invariant.

    float* out  = (float*)d_out;
    float* ctx  = out;                 // [32, 1024]
    float* wout = out + B_ * DV;       // [32, 2048]

    char* ws = (char*)d_ws;
    const size_t W1T_BYTES = (size_t)U_ * DV * 2;              // 2 MB
    const size_t T_BYTES   = (size_t)B_ * U_ * 4;              // 128 KB
    const size_t SC_BYTES  = (size_t)B_ * S_ * 4;              // 256 KB
    const size_t ABF_BYTES = (size_t)B_ * S_ * DV * 2;         // 128 MB

    if (ws_size >= W1T_BYTES + T_BYTES + SC_BYTES + ABF_BYTES) {
        // fast path: bf16 A + bf16 W1T, 8-phase 256x256 MFMA
        unsigned short* W1T = (unsigned short*)ws;
        float* t      = (float*)(ws + W1T_BYTES);
        float* scores = t + B_ * U_;
        unsigned short* Abf = (unsigned short*)(scores + B_ * S_);

        init_kernel   <<<dim3(256),      256, 0, stream>>>(b1, b2, t, ctx, scores);
        projq_kernel  <<<dim3(32, 16),   256, 0, stream>>>(query, W2, t);
        cvt_values    <<<dim3(32768),    256, 0, stream>>>(values, Abf);
        prep_w1t      <<<dim3(16, 16),   256, 0, stream>>>(W1, W1T);
        scores_mfma8  <<<dim3(1024),     512, 0, stream>>>(Abf, W1T, t, V, scores);
        softmax_kernel<<<dim3(32),       256, 0, stream>>>(scores, wout);
        context_kernel<<<dim3(32, 4, 8), 256, 0, stream>>>(values, wout, ctx);
    } else if (ws_size >= W1T_BYTES + T_BYTES + SC_BYTES) {
        // mid path: fp32 A converted in-kernel, bf16 W1T, MFMA
        unsigned short* W1T = (unsigned short*)ws;
        float* t      = (float*)(ws + W1T_BYTES);
        float* scores = t + B_ * U_;

        init_kernel   <<<dim3(256),      256, 0, stream>>>(b1, b2, t, ctx, scores);
        projq_kernel  <<<dim3(32, 16),   256, 0, stream>>>(query, W2, t);
        prep_w1t      <<<dim3(16, 16),   256, 0, stream>>>(W1, W1T);
        scores_mfma<false><<<dim3(2048), 256, 0, stream>>>(values, W1T, t, V, scores);
        softmax_kernel<<<dim3(32),       256, 0, stream>>>(scores, wout);
        context_kernel<<<dim3(32, 4, 8), 256, 0, stream>>>(values, wout, ctx);
    } else {
        // low path: round-1 fp32 vector kernel (384 KB ws, proven)
        float* t      = (float*)ws;
        float* scores = t + B_ * U_;

        init_kernel   <<<dim3(256),      256, 0, stream>>>(b1, b2, t, ctx, scores);
        projq_kernel  <<<dim3(32, 16),   256, 0, stream>>>(query, W2, t);
        scores_vec    <<<dim3(16, 32),   256, 0, stream>>>(values, W1, t, V, scores);
        softmax_kernel<<<dim3(32),       256, 0, stream>>>(scores, wout);
        context_kernel<<<dim3(32, 4, 8), 256, 0, stream>>>(values, wout, ctx);
    }
}